// Round 8
// baseline (1008.666 us; speedup 1.0000x reference)
//
#include <hip/hip_runtime.h>
#include <math.h>

// ---------- problem constants ----------
constexpr int SEQ_T = 72;
constexpr int FDIM  = 64;
constexpr int UNITS = 256;
constexpr int U4    = 1024;
constexpr int KTOT  = 320;   // FDIM + UNITS (10 k-chunks of 32)
constexpr int BATCH = 4096;

// LDS layout (dynamic, bytes)
constexpr int OFF_HB   = 0;                    // 2 parities x 8192 B (h frag blobs)
constexpr int OFF_XB   = 16384;                // 2 x 16 x 68 f32 = 8704 B
constexpr int XB_PITCH = 68;
constexpr int OFF_WL   = 25088;                // 2 kc x 64 KB weight cache
constexpr int LDS_BYTES = 25088 + 131072;      // 156160 <= 160 KiB

using bf16x8 = __attribute__((ext_vector_type(8))) short;
using f32x4  = __attribute__((ext_vector_type(4))) float;

// Opaque pin: forbids rematerialization/sinking of the loaded fragment.
#define PIN(x) asm volatile("" : "+v"(x))

__device__ __forceinline__ float sigmoid_fast(float x) {
    return 1.0f / (1.0f + __expf(-x));
}
__device__ __forceinline__ float tanh_fast(float x) {
    float ax = fabsf(x);
    float e  = __expf(2.0f * ax);
    float t  = 1.0f - 2.0f / (e + 1.0f);
    return copysignf(t, x);
}
__device__ __forceinline__ unsigned short f2bf(float f) {
    union { float f; unsigned u; } v; v.f = f;
    unsigned r = (v.u + 0x7FFFu + ((v.u >> 16) & 1u)) >> 16;   // RNE
    return (unsigned short)r;
}
__device__ __forceinline__ bf16x8 pack8(float4 a, float4 b) {
    bf16x8 p;
    p[0] = (short)f2bf(a.x); p[1] = (short)f2bf(a.y);
    p[2] = (short)f2bf(a.z); p[3] = (short)f2bf(a.w);
    p[4] = (short)f2bf(b.x); p[5] = (short)f2bf(b.y);
    p[6] = (short)f2bf(b.z); p[7] = (short)f2bf(b.w);
    return p;
}

// ---------- prep: z-weights as MFMA B-fragment blobs ----------
// blob idx = ((w*10 + kc)*8 + ct)*64 + l, 8 bf16 each.
// col = (ct>>1)*256 + w*32 + (ct&1)*16 + (l&15); k = kc*32 + (l>>4)*8 + e.
__global__ void prep_wblob(const float* __restrict__ W, const float* __restrict__ U,
                           unsigned short* __restrict__ Wblob) {
    int id = blockIdx.x * 256 + threadIdx.x;    // 40960
    int l  = id & 63;
    int ct = (id >> 6) & 7;
    int wk = id >> 9;                           // w*10 + kc
    int kc = wk % 10, w = wk / 10;
    int col = (ct >> 1) * 256 + w * 32 + (ct & 1) * 16 + (l & 15);
    int kb  = kc * 32 + (l >> 4) * 8;
    bf16x8 v;
    #pragma unroll
    for (int e = 0; e < 8; ++e) {
        int k = kb + e;
        float f = (k < FDIM) ? W[(size_t)k * U4 + col] : U[(size_t)(k - FDIM) * U4 + col];
        v[e] = (short)f2bf(f);
    }
    *reinterpret_cast<bf16x8*>(Wblob + (size_t)id * 8) = v;
}

// ---------- prep: dense weights as B-fragment blobs ----------
__global__ void prep_wdblob(const float* __restrict__ Wd, unsigned short* __restrict__ Wdblob) {
    int id = blockIdx.x * 256 + threadIdx.x;    // 2048
    int l   = id & 63;
    int kcd = (id >> 6) & 7;
    int w   = id >> 9;
    int f   = w * 16 + (l & 15);
    int kb  = kcd * 32 + (l >> 4) * 8;
    bf16x8 v;
    #pragma unroll
    for (int e = 0; e < 8; ++e)
        v[e] = (short)f2bf(Wd[(size_t)(kb + e) * FDIM + f]);
    *reinterpret_cast<bf16x8*>(Wdblob + (size_t)id * 8) = v;
}

// ---------- persistent, fully block-local LSTM ----------
// grid 256 x 512 (8 waves, 2 waves/SIMD). Block owns 16 batch rows, ALL 1024 z-cols;
// wave w owns units [w*32,w*32+32) x 4 gates.
// Weights: kc0-3 VGPR-static, PINNED via opaque asm (128 regs); kc4,5 LDS-cached
// once (128 KB); kc6-9 streamed from L2 via plain coalesced loads.
// h double-buffered in LDS by parity; h/c/pred never leave the block.
__global__ void
__attribute__((amdgpu_flat_work_group_size(512, 512), amdgpu_waves_per_eu(2, 2)))
lstm_persistent(
    const float* __restrict__ inputs,          // [B][72][64] fp32
    const float* __restrict__ bias,            // [1024] fp32
    const unsigned short* __restrict__ Wblob,  // frag-ordered z-weights (640 KB)
    const unsigned short* __restrict__ Wdblob, // frag-ordered dense weights (32 KB)
    const float* __restrict__ bd,              // [64] fp32
    float* __restrict__ out,                   // [B][out_steps][64] fp32
    int out_steps)
{
    extern __shared__ char smem[];
    unsigned short* hb = (unsigned short*)(smem + OFF_HB);   // [2][4096] shorts
    float*          xb = (float*)(smem + OFF_XB);            // [2][16*68] f32
    char*           WL = smem + OFF_WL;                      // [2][8][8][64][16B]

    const int tid = threadIdx.x;
    const int w = tid >> 6, lane = tid & 63;
    const int l16 = lane & 15, hi4 = lane >> 4;
    const int bb = blockIdx.x * 16;

    auto blob = [&](int kc, int ct) -> const bf16x8* {
        return reinterpret_cast<const bf16x8*>(
            Wblob + (size_t)(((w * 10 + kc) * 8 + ct) * 64 + lane) * 8);
    };

    // zero h blob parity 0 (8192 B, 16 B/thread)
    *reinterpret_cast<bf16x8*>(hb + tid * 8) = (bf16x8){0, 0, 0, 0, 0, 0, 0, 0};

    // ---- LDS weight cache: kc4,5 (own wave's slice) ----
    #pragma unroll
    for (int i = 0; i < 2; ++i)
        #pragma unroll
        for (int ct = 0; ct < 8; ++ct)
            *reinterpret_cast<bf16x8*>(WL + (i * 8 + w) * 8192 + ct * 1024 + lane * 16) =
                *blob(4 + i, ct);

    // ---- static weight fragments kc0-3 (W kc0,1 + U kc2,3): 128 VGPRs, pinned ----
    bf16x8 Bs[4][8];
    #pragma unroll
    for (int kc = 0; kc < 4; ++kc)
        #pragma unroll
        for (int ct = 0; ct < 8; ++ct) {
            Bs[kc][ct] = *blob(kc, ct);
            PIN(Bs[kc][ct]);
        }

    float bz[4][2];
    #pragma unroll
    for (int g = 0; g < 4; ++g)
        #pragma unroll
        for (int ut = 0; ut < 2; ++ut)
            bz[g][ut] = bias[g * 256 + w * 32 + ut * 16 + l16];
    const float bdv = bd[(w & 3) * 16 + l16];

    float c_reg[2][4];
    #pragma unroll
    for (int ut = 0; ut < 2; ++ut)
        #pragma unroll
        for (int j = 0; j < 4; ++j) c_reg[ut][j] = 0.0f;

    const int tmax = SEQ_T + out_steps - 1;    // 95

    #pragma unroll 1
    for (int t = 0; ; ++t) {
        const int p = t & 1;

        // ================ dense head (decode steps) ================
        if (t >= SEQ_T) {
            __syncthreads();                   // B0: h_t visible in hb[p]
            if (w < 4) {
                f32x4 accp = {0.f, 0.f, 0.f, 0.f};
                #pragma unroll
                for (int kcd = 0; kcd < 8; ++kcd) {
                    bf16x8 a = *reinterpret_cast<const bf16x8*>(
                        hb + p * 4096 + (kcd * 64 + lane) * 8);
                    bf16x8 bw = *reinterpret_cast<const bf16x8*>(
                        Wdblob + (size_t)(((w * 8 + kcd) * 64) + lane) * 8);
                    accp = __builtin_amdgcn_mfma_f32_16x16x32_bf16(a, bw, accp, 0, 0, 0);
                }
                const int s = t - SEQ_T;
                const int f = w * 16 + l16;
                #pragma unroll
                for (int j = 0; j < 4; ++j) {
                    int r = hi4 * 4 + j;
                    float v = accp[j] + bdv;
                    out[((size_t)(bb + r) * out_steps + s) * FDIM + f] = v;
                    xb[p * (16 * XB_PITCH) + r * XB_PITCH + f] = v;   // feedback x_t
                }
            }
        }
        if (t == tmax) break;
        __syncthreads();                       // B1: hb[p] + x source ready

        // ================ z = [x|h] @ [W;U] ================
        // stream kc6,7 (issued first; consumed after statics/LDS chunks)
        bf16x8 s6[8], s7[8], s8[8], s9[8];
        #pragma unroll
        for (int ct = 0; ct < 8; ++ct) s6[ct] = *blob(6, ct);
        #pragma unroll
        for (int ct = 0; ct < 8; ++ct) s7[ct] = *blob(7, ct);

        // x A-frags
        bf16x8 ax0, ax1;
        if (t < SEQ_T) {
            const float* xr = inputs + ((size_t)(bb + l16) * SEQ_T + t) * FDIM + hi4 * 8;
            ax0 = pack8(*reinterpret_cast<const float4*>(xr),
                        *reinterpret_cast<const float4*>(xr + 4));
            ax1 = pack8(*reinterpret_cast<const float4*>(xr + 32),
                        *reinterpret_cast<const float4*>(xr + 36));
        } else {
            const float* xr = xb + p * (16 * XB_PITCH) + l16 * XB_PITCH + hi4 * 8;
            ax0 = pack8(*reinterpret_cast<const float4*>(xr),
                        *reinterpret_cast<const float4*>(xr + 4));
            ax1 = pack8(*reinterpret_cast<const float4*>(xr + 32),
                        *reinterpret_cast<const float4*>(xr + 36));
        }

        f32x4 acc[8];
        #pragma unroll
        for (int ct = 0; ct < 8; ++ct) acc[ct] = (f32x4){0.f, 0.f, 0.f, 0.f};

        // kc0,1: x part (statics)
        #pragma unroll
        for (int ct = 0; ct < 8; ++ct)
            acc[ct] = __builtin_amdgcn_mfma_f32_16x16x32_bf16(ax0, Bs[0][ct], acc[ct], 0, 0, 0);
        #pragma unroll
        for (int ct = 0; ct < 8; ++ct)
            acc[ct] = __builtin_amdgcn_mfma_f32_16x16x32_bf16(ax1, Bs[1][ct], acc[ct], 0, 0, 0);

        // kc2,3: h part (statics)
        #pragma unroll
        for (int kc = 2; kc < 4; ++kc) {
            bf16x8 a = *reinterpret_cast<const bf16x8*>(
                hb + p * 4096 + ((kc - 2) * 64 + lane) * 8);
            #pragma unroll
            for (int ct = 0; ct < 8; ++ct)
                acc[ct] = __builtin_amdgcn_mfma_f32_16x16x32_bf16(a, Bs[kc][ct], acc[ct], 0, 0, 0);
        }

        // kc4,5: h part (LDS weight cache)
        #pragma unroll
        for (int i = 0; i < 2; ++i) {
            bf16x8 a = *reinterpret_cast<const bf16x8*>(
                hb + p * 4096 + ((2 + i) * 64 + lane) * 8);
            #pragma unroll
            for (int ct = 0; ct < 8; ++ct) {
                bf16x8 bw = *reinterpret_cast<const bf16x8*>(
                    WL + (i * 8 + w) * 8192 + ct * 1024 + lane * 16);
                acc[ct] = __builtin_amdgcn_mfma_f32_16x16x32_bf16(a, bw, acc[ct], 0, 0, 0);
            }
        }

        // kc6: consume s6, issue s8
        {
            bf16x8 a = *reinterpret_cast<const bf16x8*>(hb + p * 4096 + (4 * 64 + lane) * 8);
            #pragma unroll
            for (int ct = 0; ct < 8; ++ct)
                acc[ct] = __builtin_amdgcn_mfma_f32_16x16x32_bf16(a, s6[ct], acc[ct], 0, 0, 0);
            #pragma unroll
            for (int ct = 0; ct < 8; ++ct) s8[ct] = *blob(8, ct);
        }
        // kc7: consume s7, issue s9
        {
            bf16x8 a = *reinterpret_cast<const bf16x8*>(hb + p * 4096 + (5 * 64 + lane) * 8);
            #pragma unroll
            for (int ct = 0; ct < 8; ++ct)
                acc[ct] = __builtin_amdgcn_mfma_f32_16x16x32_bf16(a, s7[ct], acc[ct], 0, 0, 0);
            #pragma unroll
            for (int ct = 0; ct < 8; ++ct) s9[ct] = *blob(9, ct);
        }
        // kc8, kc9
        {
            bf16x8 a = *reinterpret_cast<const bf16x8*>(hb + p * 4096 + (6 * 64 + lane) * 8);
            #pragma unroll
            for (int ct = 0; ct < 8; ++ct)
                acc[ct] = __builtin_amdgcn_mfma_f32_16x16x32_bf16(a, s8[ct], acc[ct], 0, 0, 0);
        }
        {
            bf16x8 a = *reinterpret_cast<const bf16x8*>(hb + p * 4096 + (7 * 64 + lane) * 8);
            #pragma unroll
            for (int ct = 0; ct < 8; ++ct)
                acc[ct] = __builtin_amdgcn_mfma_f32_16x16x32_bf16(a, s9[ct], acc[ct], 0, 0, 0);
        }

        // ================ gates + state update; h_{t+1} -> hb[1-p] ================
        #pragma unroll
        for (int ut = 0; ut < 2; ++ut) {
            #pragma unroll
            for (int j = 0; j < 4; ++j) {
                float zi = acc[0 + ut][j] + bz[0][ut];
                float zf = acc[2 + ut][j] + bz[1][ut];
                float zg = acc[4 + ut][j] + bz[2][ut];
                float zo = acc[6 + ut][j] + bz[3][ut];
                float ig = sigmoid_fast(zi);
                float fg = sigmoid_fast(zf);
                float og = sigmoid_fast(zo);
                float cn = fg * c_reg[ut][j] + ig * tanh_fast(zg);
                c_reg[ut][j] = cn;
                float hv = og * tanh_fast(cn);
                int r  = hi4 * 4 + j;
                int lp = (ut * 2 + (l16 >> 3)) * 16 + r;
                hb[(1 - p) * 4096 + w * 512 + lp * 8 + (l16 & 7)] = f2bf(hv);
            }
        }
    }
}

extern "C" void kernel_launch(void* const* d_in, const int* in_sizes, int n_in,
                              void* d_out, int out_size, void* d_ws, size_t ws_size,
                              hipStream_t stream) {
    const float* inputs = (const float*)d_in[0];
    const float* W      = (const float*)d_in[1];
    const float* U      = (const float*)d_in[2];
    const float* b      = (const float*)d_in[3];
    const float* Wd     = (const float*)d_in[4];
    const float* bd     = (const float*)d_in[5];
    float* out = (float*)d_out;

    const int out_steps = out_size / (BATCH * FDIM);   // 24

    char* ws = (char*)d_ws;
    unsigned short* Wblob  = (unsigned short*)(ws);               // 640 KB
    unsigned short* Wdblob = (unsigned short*)(ws + (1u << 20));  // 32 KB

    prep_wblob<<<160, 256, 0, stream>>>(W, U, Wblob);
    prep_wdblob<<<8, 256, 0, stream>>>(Wd, Wdblob);

    (void)hipFuncSetAttribute((const void*)lstm_persistent,
                              hipFuncAttributeMaxDynamicSharedMemorySize, LDS_BYTES);

    lstm_persistent<<<dim3(BATCH / 16), dim3(512), LDS_BYTES, stream>>>(
        inputs, b, Wblob, Wdblob, bd, out, out_steps);
}